// Round 1
// baseline (157.129 us; speedup 1.0000x reference)
//
#include <hip/hip_runtime.h>
#include <hip/hip_bf16.h>
#include <cstdint>
#include <cstddef>

// Problem dims (fixed by the reference: B=4, C=256, H=W=64)
#define C_    256
#define C8_   32
#define NPIX  4096
#define BATCH 4
#define OUT_ELEMS (BATCH * C_ * NPIX)   // 4,194,304 floats, then attention [4096][4096]

typedef short bf16x8 __attribute__((ext_vector_type(8)));   // 8 bf16 in 4 VGPRs
typedef float f32x4  __attribute__((ext_vector_type(4)));

static __device__ __forceinline__ unsigned short f2bf(float f) {
    union { float f; unsigned u; } v; v.f = f;
    unsigned r = v.u + 0x7fff + ((v.u >> 16) & 1);   // RNE
    return (unsigned short)(r >> 16);
}

static __device__ __forceinline__ f32x4 mfma16(bf16x8 a, bf16x8 b, f32x4 c) {
    return __builtin_amdgcn_mfma_f32_16x16x32_bf16(a, b, c, 0, 0, 0);
}

// ---------------------------------------------------------------------------
// K1: q/k (and v if gamma!=0) 1x1-conv projections; fuses out=x copy (gamma==0).
//   qT,kT: bf16 [B][N][32]  (c contiguous -> natural MFMA fragment loads)
//   vB   : bf16 [B][C][N]   (j contiguous -> natural PV B-fragment loads)
// Grid: (N/64, B), block 256 (4 waves). Wave w owns outputs o = w + 4*m.
// ---------------------------------------------------------------------------
__global__ __launch_bounds__(256) void k_proj(
    const float* __restrict__ x,
    const float* __restrict__ Wq, const float* __restrict__ bq,
    const float* __restrict__ Wk, const float* __restrict__ bk,
    const float* __restrict__ Wv, const float* __restrict__ bv,
    const float* __restrict__ gamma,
    float* __restrict__ out,
    unsigned short* __restrict__ qT,
    unsigned short* __restrict__ kT,
    unsigned short* __restrict__ vB)
{
    const int b    = blockIdx.y;
    const int n0   = blockIdx.x * 64;
    const int t    = threadIdx.x;
    const int lane = t & 63;
    const int wavei = __builtin_amdgcn_readfirstlane(t >> 6);  // 0..3, wave-uniform
    const int n    = n0 + lane;
    const bool g0  = (gamma[0] == 0.0f);

    const float* xb = x + (size_t)b * C_ * NPIX;
    float* outb = out + (size_t)b * C_ * NPIX;

    if (g0 && b > 0) {
        // gamma==0: out = x (attention for b>0 never observed). Pure copy.
        for (int c = wavei; c < C_; c += 4)
            outb[(size_t)c * NPIX + n] = xb[(size_t)c * NPIX + n];
        return;
    }

    // --- q,k projection (64 outputs, 16 per thread across the c loop) ---
    float acc[16];
#pragma unroll
    for (int m = 0; m < 16; ++m) {
        int o = wavei + 4 * m;
        acc[m] = (o < C8_) ? bq[o] : bk[o - C8_];
    }
    const bool do_copy = g0 && (wavei == 0);   // only b==0 reaches here with g0
    for (int c = 0; c < C_; ++c) {
        float xv = xb[(size_t)c * NPIX + n];
        if (do_copy) outb[(size_t)c * NPIX + n] = xv;
#pragma unroll
        for (int m = 0; m < 16; ++m) {
            int o = wavei + 4 * m;
            float w = (o < C8_) ? Wq[o * C_ + c] : Wk[(o - C8_) * C_ + c];
            acc[m] += w * xv;
        }
    }
#pragma unroll
    for (int m = 0; m < 16; ++m) {
        int o = wavei + 4 * m;
        unsigned short h = f2bf(acc[m]);
        if (o < C8_) qT[((size_t)b * NPIX + n) * C8_ + o] = h;
        else         kT[((size_t)b * NPIX + n) * C8_ + (o - C8_)] = h;
    }

    // --- v projection: only needed when gamma != 0 ---
    if (!g0) {
        for (int och = 0; och < 8; ++och) {
            float vacc[8];
#pragma unroll
            for (int m2 = 0; m2 < 8; ++m2) vacc[m2] = bv[wavei + 4 * (och * 8 + m2)];
            for (int c = 0; c < C_; ++c) {
                float xv = xb[(size_t)c * NPIX + n];
#pragma unroll
                for (int m2 = 0; m2 < 8; ++m2) {
                    int o = wavei + 4 * (och * 8 + m2);
                    vacc[m2] += Wv[o * C_ + c] * xv;
                }
            }
#pragma unroll
            for (int m2 = 0; m2 < 8; ++m2) {
                int o = wavei + 4 * (och * 8 + m2);
                vB[((size_t)b * C_ + o) * NPIX + n] = f2bf(vacc[m2]);
            }
        }
    }
}

// ---------------------------------------------------------------------------
// K2: fused energy + softmax (+ attention write for b==0; + PV + out if gamma!=0)
// Block = 16 query rows (i-tile), 512 threads = 8 waves; wave w owns j in
// [w*512, w*512+512). Energy via mfma(Kt, Qt): D[j_local, i_local] so each
// lane holds ONE query row i = i0+(lane&15) and 128 j-values in registers ->
// softmax reductions are in-lane + shfl_xor(16,32) + 8-wave LDS reduce.
// ---------------------------------------------------------------------------
__global__ __launch_bounds__(512) void k_attn(
    const float* __restrict__ x,
    const unsigned short* __restrict__ qT,
    const unsigned short* __restrict__ kT,
    const unsigned short* __restrict__ vB,
    const float* __restrict__ gamma,
    float* __restrict__ out,
    float* __restrict__ attn)
{
    const int b = blockIdx.y;
    const float g = gamma[0];
    if (g == 0.0f && b > 0) return;   // block-uniform

    const int i0   = blockIdx.x * 16;
    const int t    = threadIdx.x;
    const int lane = t & 63;
    const int wavei = __builtin_amdgcn_readfirstlane(t >> 6);  // 0..7
    const int li   = lane & 15;
    const int lg   = lane >> 4;       // 0..3

    __shared__ float red[8][16];
    __shared__ unsigned short pst[16][520];   // PV staging (gamma!=0 only)

    const unsigned short* qTb = qT + (size_t)b * NPIX * C8_;
    const unsigned short* kTb = kT + (size_t)b * NPIX * C8_;

    // B fragment (Q): rows i0+li, k-elems lg*8..lg*8+7 — loaded once.
    bf16x8 qf = *(const bf16x8*)(qTb + (size_t)(i0 + li) * C8_ + lg * 8);

    const int jw = wavei * 512;

    // energy: 32 MFMAs, K=32 == C8 so a single MFMA per 16x16 tile.
    f32x4 acc[32];
#pragma unroll
    for (int s = 0; s < 32; ++s) {
        bf16x8 kf = *(const bf16x8*)(kTb + (size_t)(jw + s * 16 + li) * C8_ + lg * 8);
        f32x4 z = {0.f, 0.f, 0.f, 0.f};
        acc[s] = mfma16(kf, qf, z);   // D[j,i] = sum_c k[c,j] q[c,i]
    }

    // --- row max (per lane: one i-row, 128 j-values) ---
    float m = -1e30f;
#pragma unroll
    for (int s = 0; s < 32; ++s) {
        m = fmaxf(m, fmaxf(fmaxf(acc[s][0], acc[s][1]), fmaxf(acc[s][2], acc[s][3])));
    }
    m = fmaxf(m, __shfl_xor(m, 16, 64));
    m = fmaxf(m, __shfl_xor(m, 32, 64));
    if (lane < 16) red[wavei][lane] = m;
    __syncthreads();
    float mg = red[0][li];
#pragma unroll
    for (int w = 1; w < 8; ++w) mg = fmaxf(mg, red[w][li]);
    __syncthreads();   // protect red before reuse

    // --- exp + row sum (p overwrites acc) ---
    const float LOG2E = 1.44269504088896340736f;
    float ssum = 0.f;
#pragma unroll
    for (int s = 0; s < 32; ++s) {
#pragma unroll
        for (int u = 0; u < 4; ++u) {
            float p = exp2f((acc[s][u] - mg) * LOG2E);
            acc[s][u] = p;
            ssum += p;
        }
    }
    ssum += __shfl_xor(ssum, 16, 64);
    ssum += __shfl_xor(ssum, 32, 64);
    if (lane < 16) red[wavei][lane] = ssum;
    __syncthreads();
    float l = 0.f;
#pragma unroll
    for (int w = 0; w < 8; ++w) l += red[w][li];
    const float inv = 1.0f / l;

    // --- attention_map write (batch 0): fully-coalesced float4 stores ---
    if (b == 0) {
        float* ap = attn + (size_t)(i0 + li) * NPIX + jw + lg * 4;
#pragma unroll
        for (int s = 0; s < 32; ++s) {
            f32x4 v4 = acc[s] * inv;
            *(f32x4*)(ap + s * 16) = v4;
        }
    }

    // --- general path (gamma != 0): PV + out = gamma*attnout + x ---
    if (g != 0.0f) {
        f32x4 o0 = {0.f, 0.f, 0.f, 0.f};
        f32x4 o1 = {0.f, 0.f, 0.f, 0.f};
        const unsigned short* vb = vB + (size_t)b * C_ * NPIX;
        for (int st = 0; st < 8; ++st) {
            __syncthreads();
            if (wavei == st) {   // stage this wave's normalized P subtile [16 i][512 j]
#pragma unroll
                for (int s = 0; s < 32; ++s) {
#pragma unroll
                    for (int r = 0; r < 4; ++r)
                        pst[li][s * 16 + lg * 4 + r] = f2bf(acc[s][r] * inv);
                }
            }
            __syncthreads();
            const int jbase = st * 512;
#pragma unroll
            for (int ks = 0; ks < 16; ++ks) {
                bf16x8 af = *(const bf16x8*)(&pst[li][ks * 32 + lg * 8]);  // A[i, j]
                const unsigned short* vp0 =
                    vb + (size_t)(wavei * 32 + li) * NPIX + jbase + ks * 32 + lg * 8;
                bf16x8 vf0 = *(const bf16x8*)vp0;               // B[j, c-tile0]
                o0 = mfma16(af, vf0, o0);
                bf16x8 vf1 = *(const bf16x8*)(vp0 + (size_t)16 * NPIX);  // c-tile1
                o1 = mfma16(af, vf1, o1);
            }
        }
        // D2[i, c]: lane -> c = c0 + li, i = i0 + lg*4 + r (4 consecutive i = float4)
        const float* xbt = x + (size_t)b * C_ * NPIX;
        float* outb = out + (size_t)b * C_ * NPIX;
        {
            int c = wavei * 32 + li;
            f32x4 xv = *(const f32x4*)(xbt + (size_t)c * NPIX + i0 + lg * 4);
            f32x4 r0 = o0 * g + xv;
            *(f32x4*)(outb + (size_t)c * NPIX + i0 + lg * 4) = r0;
            c += 16;
            f32x4 xv1 = *(const f32x4*)(xbt + (size_t)c * NPIX + i0 + lg * 4);
            f32x4 r1 = o1 * g + xv1;
            *(f32x4*)(outb + (size_t)c * NPIX + i0 + lg * 4) = r1;
        }
    }
}

extern "C" void kernel_launch(void* const* d_in, const int* in_sizes, int n_in,
                              void* d_out, int out_size, void* d_ws, size_t ws_size,
                              hipStream_t stream) {
    (void)in_sizes; (void)n_in; (void)out_size; (void)ws_size;
    const float* x     = (const float*)d_in[0];
    const float* Wq    = (const float*)d_in[1];
    const float* bq    = (const float*)d_in[2];
    const float* Wk    = (const float*)d_in[3];
    const float* bk    = (const float*)d_in[4];
    const float* Wv    = (const float*)d_in[5];
    const float* bv    = (const float*)d_in[6];
    const float* gamma = (const float*)d_in[7];

    float* out  = (float*)d_out;
    float* attn = out + OUT_ELEMS;

    unsigned short* qT = (unsigned short*)d_ws;                       // 1 MB
    unsigned short* kT = qT + (size_t)BATCH * NPIX * C8_;             // 1 MB
    unsigned short* vB = kT + (size_t)BATCH * NPIX * C8_;             // 8 MB (gamma!=0 only)

    dim3 g1(NPIX / 64, BATCH);
    k_proj<<<g1, 256, 0, stream>>>(x, Wq, bq, Wk, bk, Wv, bv, gamma, out, qT, kT, vB);

    dim3 g2(NPIX / 16, BATCH);
    k_attn<<<g2, 512, 0, stream>>>(x, qT, kT, vB, gamma, out, attn);
}

// Round 3
// 48.065 us; speedup vs baseline: 3.2691x; 3.2691x over previous
//
#include <hip/hip_runtime.h>
#include <hip/hip_bf16.h>
#include <cstdint>
#include <cstddef>

// Problem dims (fixed by the reference: B=4, C=256, H=W=64)
#define C_    256
#define C8_   32
#define NPIX  4096
#define BATCH 4
#define OUT_ELEMS (BATCH * C_ * NPIX)   // 4,194,304 floats, then attention [4096][4096]

typedef short bf16x8 __attribute__((ext_vector_type(8)));   // 8 bf16 in 4 VGPRs
typedef float f32x4  __attribute__((ext_vector_type(4)));

static __device__ __forceinline__ unsigned short f2bf(float f) {
    union { float f; unsigned u; } v; v.f = f;
    unsigned r = v.u + 0x7fff + ((v.u >> 16) & 1);   // RNE
    return (unsigned short)(r >> 16);
}

static __device__ __forceinline__ f32x4 mfma16(bf16x8 a, bf16x8 b, f32x4 c) {
    return __builtin_amdgcn_mfma_f32_16x16x32_bf16(a, b, c, 0, 0, 0);
}

// ---------------------------------------------------------------------------
// K0: out = x (residual with gamma==0 contributes nothing else; when gamma!=0,
// k_attn later overwrites out with the full result). Fat grid-stride copy.
// ---------------------------------------------------------------------------
__global__ __launch_bounds__(256) void k_copy(const float* __restrict__ x,
                                              float* __restrict__ out) {
    const size_t n4 = (size_t)OUT_ELEMS / 4;
    const f32x4* src = (const f32x4*)x;
    f32x4* dst = (f32x4*)out;
    for (size_t i = (size_t)blockIdx.x * blockDim.x + threadIdx.x; i < n4;
         i += (size_t)gridDim.x * blockDim.x)
        dst[i] = src[i];
}

// ---------------------------------------------------------------------------
// K1a: q/k projection. Grid (N/64, 8, B), block 256 (4 waves).
// Wave w of block (bx, by, b) computes outputs o = (by*4+w)*2, +1 for the
// 64-pixel tile n0 = bx*64. 2 accumulators/thread, unroll-8 c loop keeps
// 8 independent global loads in flight. For gamma==0 only b==0 is needed.
//   qT,kT: bf16 [B][N][32]  (c contiguous -> natural MFMA fragment loads)
// ---------------------------------------------------------------------------
__global__ __launch_bounds__(256) void k_projqk(
    const float* __restrict__ x,
    const float* __restrict__ Wq, const float* __restrict__ bq,
    const float* __restrict__ Wk, const float* __restrict__ bk,
    const float* __restrict__ gamma,
    unsigned short* __restrict__ qT,
    unsigned short* __restrict__ kT)
{
    const int b = blockIdx.z;
    if (gamma[0] == 0.0f && b > 0) return;   // attention only observed at b==0

    const int n     = blockIdx.x * 64 + (threadIdx.x & 63);
    const int w     = __builtin_amdgcn_readfirstlane(threadIdx.x >> 6);  // 0..3
    const int og    = (blockIdx.y * 4 + w) * 2;   // 0,2,..,62 (pair stays in one half)
    const bool is_q = (og < C8_);
    const int  o0   = is_q ? og : og - C8_;

    const float* Wrow0 = (is_q ? Wq : Wk) + (size_t)o0 * C_;
    const float* Wrow1 = Wrow0 + C_;
    float acc0 = is_q ? bq[o0] : bk[o0];
    float acc1 = is_q ? bq[o0 + 1] : bk[o0 + 1];

    const float* xb = x + (size_t)b * C_ * NPIX + n;
#pragma unroll 8
    for (int c = 0; c < C_; ++c) {
        float xv = xb[(size_t)c * NPIX];
        acc0 = fmaf(Wrow0[c], xv, acc0);
        acc1 = fmaf(Wrow1[c], xv, acc1);
    }

    unsigned short* dst = (is_q ? qT : kT) + ((size_t)b * NPIX + n) * C8_ + o0;
    dst[0] = f2bf(acc0);
    dst[1] = f2bf(acc1);
}

// ---------------------------------------------------------------------------
// K1b: v projection — only needed when gamma != 0 (correctness path).
// Grid (N/64, 16, B), block 256: wave w computes 4 outputs o=(by*4+w)*4..+3.
//   vB: bf16 [B][C][N]  (j contiguous -> natural PV B-fragment loads)
// ---------------------------------------------------------------------------
__global__ __launch_bounds__(256) void k_projv(
    const float* __restrict__ x,
    const float* __restrict__ Wv, const float* __restrict__ bv,
    const float* __restrict__ gamma,
    unsigned short* __restrict__ vB)
{
    if (gamma[0] == 0.0f) return;
    const int b  = blockIdx.z;
    const int n  = blockIdx.x * 64 + (threadIdx.x & 63);
    const int w  = __builtin_amdgcn_readfirstlane(threadIdx.x >> 6);
    const int o0 = (blockIdx.y * 4 + w) * 4;

    float acc[4];
#pragma unroll
    for (int m = 0; m < 4; ++m) acc[m] = bv[o0 + m];

    const float* xb = x + (size_t)b * C_ * NPIX + n;
#pragma unroll 4
    for (int c = 0; c < C_; ++c) {
        float xv = xb[(size_t)c * NPIX];
#pragma unroll
        for (int m = 0; m < 4; ++m) acc[m] = fmaf(Wv[(o0 + m) * C_ + c], xv, acc[m]);
    }
#pragma unroll
    for (int m = 0; m < 4; ++m)
        vB[((size_t)b * C_ + o0 + m) * NPIX + n] = f2bf(acc[m]);
}

// ---------------------------------------------------------------------------
// K2: fused energy + softmax (+ attention write for b==0; + PV + out if gamma!=0)
// Block = 16 query rows (i-tile), 512 threads = 8 waves; wave w owns j in
// [w*512, w*512+512). Energy via mfma(Kt, Qt): D[j_local, i_local] so each
// lane holds ONE query row i = i0+(lane&15) and 128 j-values in registers ->
// softmax reductions are in-lane + shfl_xor(16,32) + 8-wave LDS reduce.
// ---------------------------------------------------------------------------
__global__ __launch_bounds__(512) void k_attn(
    const float* __restrict__ x,
    const unsigned short* __restrict__ qT,
    const unsigned short* __restrict__ kT,
    const unsigned short* __restrict__ vB,
    const float* __restrict__ gamma,
    float* __restrict__ out,
    float* __restrict__ attn)
{
    const int b = blockIdx.y;
    const float g = gamma[0];
    if (g == 0.0f && b > 0) return;   // block-uniform

    const int i0   = blockIdx.x * 16;
    const int t    = threadIdx.x;
    const int lane = t & 63;
    const int wavei = __builtin_amdgcn_readfirstlane(t >> 6);  // 0..7
    const int li   = lane & 15;
    const int lg   = lane >> 4;       // 0..3

    __shared__ float red[8][16];
    __shared__ unsigned short pst[16][520];   // PV staging (gamma!=0 only)

    const unsigned short* qTb = qT + (size_t)b * NPIX * C8_;
    const unsigned short* kTb = kT + (size_t)b * NPIX * C8_;

    // B fragment (Q): rows i0+li, k-elems lg*8..lg*8+7 — loaded once.
    bf16x8 qf = *(const bf16x8*)(qTb + (size_t)(i0 + li) * C8_ + lg * 8);

    const int jw = wavei * 512;

    // energy: 32 MFMAs, K=32 == C8 so a single MFMA per 16x16 tile.
    f32x4 acc[32];
#pragma unroll
    for (int s = 0; s < 32; ++s) {
        bf16x8 kf = *(const bf16x8*)(kTb + (size_t)(jw + s * 16 + li) * C8_ + lg * 8);
        f32x4 z = {0.f, 0.f, 0.f, 0.f};
        acc[s] = mfma16(kf, qf, z);   // D[j,i] = sum_c k[c,j] q[c,i]
    }

    // --- row max (per lane: one i-row, 128 j-values) ---
    float m = -1e30f;
#pragma unroll
    for (int s = 0; s < 32; ++s) {
        m = fmaxf(m, fmaxf(fmaxf(acc[s][0], acc[s][1]), fmaxf(acc[s][2], acc[s][3])));
    }
    m = fmaxf(m, __shfl_xor(m, 16, 64));
    m = fmaxf(m, __shfl_xor(m, 32, 64));
    if (lane < 16) red[wavei][lane] = m;
    __syncthreads();
    float mg = red[0][li];
#pragma unroll
    for (int w = 1; w < 8; ++w) mg = fmaxf(mg, red[w][li]);
    __syncthreads();   // protect red before reuse

    // --- exp + row sum (p overwrites acc) ---
    const float LOG2E = 1.44269504088896340736f;
    float ssum = 0.f;
#pragma unroll
    for (int s = 0; s < 32; ++s) {
#pragma unroll
        for (int u = 0; u < 4; ++u) {
            float p = exp2f((acc[s][u] - mg) * LOG2E);
            acc[s][u] = p;
            ssum += p;
        }
    }
    ssum += __shfl_xor(ssum, 16, 64);
    ssum += __shfl_xor(ssum, 32, 64);
    if (lane < 16) red[wavei][lane] = ssum;
    __syncthreads();
    float l = 0.f;
#pragma unroll
    for (int w = 0; w < 8; ++w) l += red[w][li];
    const float inv = 1.0f / l;

    // --- attention_map write (batch 0): fully-coalesced float4 stores ---
    if (b == 0) {
        float* ap = attn + (size_t)(i0 + li) * NPIX + jw + lg * 4;
#pragma unroll
        for (int s = 0; s < 32; ++s) {
            f32x4 v4 = acc[s] * inv;
            *(f32x4*)(ap + s * 16) = v4;
        }
    }

    // --- general path (gamma != 0): PV + out = gamma*attnout + x ---
    if (g != 0.0f) {
        f32x4 o0 = {0.f, 0.f, 0.f, 0.f};
        f32x4 o1 = {0.f, 0.f, 0.f, 0.f};
        const unsigned short* vb = vB + (size_t)b * C_ * NPIX;
        for (int st = 0; st < 8; ++st) {
            __syncthreads();
            if (wavei == st) {   // stage this wave's normalized P subtile [16 i][512 j]
#pragma unroll
                for (int s = 0; s < 32; ++s) {
#pragma unroll
                    for (int r = 0; r < 4; ++r)
                        pst[li][s * 16 + lg * 4 + r] = f2bf(acc[s][r] * inv);
                }
            }
            __syncthreads();
            const int jbase = st * 512;
#pragma unroll
            for (int ks = 0; ks < 16; ++ks) {
                bf16x8 af = *(const bf16x8*)(&pst[li][ks * 32 + lg * 8]);  // A[i, j]
                const unsigned short* vp0 =
                    vb + (size_t)(wavei * 32 + li) * NPIX + jbase + ks * 32 + lg * 8;
                bf16x8 vf0 = *(const bf16x8*)vp0;               // B[j, c-tile0]
                o0 = mfma16(af, vf0, o0);
                bf16x8 vf1 = *(const bf16x8*)(vp0 + (size_t)16 * NPIX);  // c-tile1
                o1 = mfma16(af, vf1, o1);
            }
        }
        // D2[i, c]: lane -> c = c0 + li, i = i0 + lg*4 + r (4 consecutive i = float4)
        const float* xbt = x + (size_t)b * C_ * NPIX;
        float* outb = out + (size_t)b * C_ * NPIX;
        {
            int c = wavei * 32 + li;
            f32x4 xv = *(const f32x4*)(xbt + (size_t)c * NPIX + i0 + lg * 4);
            f32x4 r0 = o0 * g + xv;
            *(f32x4*)(outb + (size_t)c * NPIX + i0 + lg * 4) = r0;
            c += 16;
            f32x4 xv1 = *(const f32x4*)(xbt + (size_t)c * NPIX + i0 + lg * 4);
            f32x4 r1 = o1 * g + xv1;
            *(f32x4*)(outb + (size_t)c * NPIX + i0 + lg * 4) = r1;
        }
    }
}

extern "C" void kernel_launch(void* const* d_in, const int* in_sizes, int n_in,
                              void* d_out, int out_size, void* d_ws, size_t ws_size,
                              hipStream_t stream) {
    (void)in_sizes; (void)n_in; (void)out_size; (void)ws_size;
    const float* x     = (const float*)d_in[0];
    const float* Wq    = (const float*)d_in[1];
    const float* bq    = (const float*)d_in[2];
    const float* Wk    = (const float*)d_in[3];
    const float* bk    = (const float*)d_in[4];
    const float* Wv    = (const float*)d_in[5];
    const float* bv    = (const float*)d_in[6];
    const float* gamma = (const float*)d_in[7];

    float* out  = (float*)d_out;
    float* attn = out + OUT_ELEMS;

    unsigned short* qT = (unsigned short*)d_ws;                       // 1 MB
    unsigned short* kT = qT + (size_t)BATCH * NPIX * C8_;             // 1 MB
    unsigned short* vB = kT + (size_t)BATCH * NPIX * C8_;             // 8 MB (gamma!=0 only)

    k_copy<<<2048, 256, 0, stream>>>(x, out);

    dim3 gqk(NPIX / 64, 8, BATCH);
    k_projqk<<<gqk, 256, 0, stream>>>(x, Wq, bq, Wk, bk, gamma, qT, kT);

    dim3 gv(NPIX / 64, 16, BATCH);
    k_projv<<<gv, 256, 0, stream>>>(x, Wv, bv, gamma, vB);

    dim3 g2(NPIX / 16, BATCH);
    k_attn<<<g2, 512, 0, stream>>>(x, qT, kT, vB, gamma, out, attn);
}